// Round 5
// baseline (188.471 us; speedup 1.0000x reference)
//
#include <hip/hip_runtime.h>

#define N_LABELS 45
#define N_TRIGRAMS 4000000
#define WPW 4     // words per wave
#define GRP 16    // max fast-path entries per word

// Build lower-bound offsets: off[w] = first i with seg[i] >= w, off[W] = F.
__global__ void build_offsets_kernel(const int* __restrict__ seg,
                                     int* __restrict__ off, int F, int W) {
    int i = blockIdx.x * blockDim.x + threadIdx.x;
    if (i >= F) return;
    int s = seg[i];
    int p = (i == 0) ? -1 : seg[i - 1];
    for (int w = p + 1; w <= s; ++w) off[w] = i;
    if (i == F - 1) {
        for (int w = s + 1; w <= W; ++w) off[w] = F;
    }
}

// One wave per WPW consecutive words. Lanes 0..44 own label columns.
__global__ void tagger_kernel(const int* __restrict__ feat,
                              const float* __restrict__ weights,
                              const float* __restrict__ trigram_w,
                              const int* __restrict__ off,
                              float* __restrict__ out, int W, int F) {
    int gwave = (int)((blockIdx.x * blockDim.x + threadIdx.x) >> 6);
    gwave = __builtin_amdgcn_readfirstlane(gwave);
    int lane = (int)(threadIdx.x & 63);
    int w0 = gwave * WPW;
    if (w0 >= W) return;

    int ll = (lane < N_LABELS) ? lane : 0;   // lanes 45..63 mirror lane 0

    // word boundaries (wave-uniform -> scalar loads)
    int b[WPW + 1];
    #pragma unroll
    for (int k = 0; k <= WPW; ++k) {
        int w = w0 + k;
        b[k] = off[(w < W) ? w : W];
    }

    int beg = b[0];
    // one coalesced chunk of up to 64 indices covering all WPW words
    int my = feat[min(beg + lane, F - 1)];

    float vals[WPW][GRP];
    int   tri[WPW];
    int   ncv[WPW];

    // ---- issue phase: fire all gathers, keep them in flight ----
    #pragma unroll
    for (int k = 0; k < WPW; ++k) {
        int s = b[k], e = b[k + 1];
        int len = e - s;
        int rel = s - beg;
        int avail = 64 - min(rel, 64);
        int ncov = min(min(len, GRP), avail);   // fast-covered entries
        ncv[k] = ncov;
        int lastj = (ncov > 0) ? (ncov - 1) : 0;
        tri[k] = 0;

        #pragma unroll
        for (int j = 0; j < 8; ++j) {
            int jc = (j < ncov) ? j : lastj;    // pads duplicate last entry
            int p = min(rel + jc, 63);
            int idx = __builtin_amdgcn_readlane(my, p);   // SGPR
            tri[k] += (j < ncov) ? idx : 0;
            vals[k][j] = weights[(unsigned)idx * N_LABELS + ll];
        }
        if (ncov > 8) {                          // uniform branch, ~45% taken
            #pragma unroll
            for (int j = 8; j < GRP; ++j) {
                int jc = (j < ncov) ? j : lastj;
                int p = min(rel + jc, 63);
                int idx = __builtin_amdgcn_readlane(my, p);
                tri[k] += (j < ncov) ? idx : 0;
                vals[k][j] = weights[(unsigned)idx * N_LABELS + ll];
            }
        }
    }

    // scheduling fence: loads above may not sink below this point
    asm volatile("" ::: "memory");

    // optimistic trigram gathers (overlap with consume)
    float trig[WPW];
    #pragma unroll
    for (int k = 0; k < WPW; ++k) {
        int t = tri[k];
        if (t < 0) t = 0;
        if (t >= N_TRIGRAMS) t = N_TRIGRAMS - 1;
        trig[k] = trigram_w[t];
    }

    float acc[WPW];

    // ---- consume phase ----
    #pragma unroll
    for (int k = 0; k < WPW; ++k) {
        int s = b[k], e = b[k + 1];
        int ncov = ncv[k];
        float sum;
        if (ncov > 8) {
            int pad = GRP - ncov;
            float t0 = (vals[k][0]  + vals[k][1])  + (vals[k][2]  + vals[k][3]);
            float t1 = (vals[k][4]  + vals[k][5])  + (vals[k][6]  + vals[k][7]);
            float t2 = (vals[k][8]  + vals[k][9])  + (vals[k][10] + vals[k][11]);
            float t3 = (vals[k][12] + vals[k][13]) + (vals[k][14] + vals[k][15]);
            sum = ((t0 + t1) + (t2 + t3)) - (float)pad * vals[k][GRP - 1];
        } else {
            int pad = 8 - ncov;
            float t0 = (vals[k][0] + vals[k][1]) + (vals[k][2] + vals[k][3]);
            float t1 = (vals[k][4] + vals[k][5]) + (vals[k][6] + vals[k][7]);
            sum = (t0 + t1) - (float)pad * vals[k][7];
        }
        acc[k] = sum;

        // slow remainder: len > GRP or chunk overflow (rare)
        if (s + ncov < e) {
            for (int base2 = s + ncov; base2 < e; base2 += 64) {
                int cnt = min(64, e - base2);
                int m2 = feat[base2 + ((lane < cnt) ? lane : 0)];
                for (int g = 0; g < cnt; g += 8) {
                    float v2[8];
                    int lastE = cnt - 1;
                    #pragma unroll
                    for (int j = 0; j < 8; ++j) {
                        int e2 = g + j;
                        int ec = (e2 < cnt) ? e2 : lastE;
                        int idx = __builtin_amdgcn_readlane(m2, ec);
                        tri[k] += (e2 < cnt) ? idx : 0;
                        v2[j] = weights[(unsigned)idx * N_LABELS + ll];
                    }
                    int pad2 = (g + 8 > cnt) ? (g + 8 - cnt) : 0;
                    float s01 = v2[0] + v2[1], s23 = v2[2] + v2[3];
                    float s45 = v2[4] + v2[5], s67 = v2[6] + v2[7];
                    acc[k] += ((s01 + s23) + (s45 + s67)) - (float)pad2 * v2[7];
                }
            }
            // re-do trigram with the completed index sum
            int t = tri[k];
            if (t < 0) t = 0;
            if (t >= N_TRIGRAMS) t = N_TRIGRAMS - 1;
            trig[k] = trigram_w[t];
        }
    }

    #pragma unroll
    for (int k = 0; k < WPW; ++k) {
        int w = w0 + k;
        if (lane < N_LABELS && w < W)
            out[(long long)w * N_LABELS + lane] = acc[k] + trig[k];
    }
}

extern "C" void kernel_launch(void* const* d_in, const int* in_sizes, int n_in,
                              void* d_out, int out_size, void* d_ws, size_t ws_size,
                              hipStream_t stream) {
    const int*   feat      = (const int*)d_in[0];
    const int*   seg       = (const int*)d_in[1];
    const float* weights   = (const float*)d_in[2];
    const float* trigram_w = (const float*)d_in[3];
    float*       out       = (float*)d_out;

    int F = in_sizes[0];
    int W = out_size / N_LABELS;

    int* off = (int*)d_ws;  // (W+1) ints

    {
        int threads = 256;
        int blocks = (F + threads - 1) / threads;
        build_offsets_kernel<<<blocks, threads, 0, stream>>>(seg, off, F, W);
    }
    {
        int threads = 256;  // 4 waves per block
        int wavesPerBlock = threads / 64;
        int nWaves = (W + WPW - 1) / WPW;
        int blocks = (nWaves + wavesPerBlock - 1) / wavesPerBlock;
        tagger_kernel<<<blocks, threads, 0, stream>>>(feat, weights, trigram_w,
                                                      off, out, W, F);
    }
}

// Round 6
// 180.340 us; speedup vs baseline: 1.0451x; 1.0451x over previous
//
#include <hip/hip_runtime.h>

#define N_LABELS 45
#define N_TRIGRAMS 4000000
#define WPW 4        // words per wave
#define GRP 16       // max fast-path entries per word
#define ROWSTRIDE 64 // padded bf16 row: 64*2 = 128 B = exactly one cache line

// Build lower-bound offsets: off[w] = first i with seg[i] >= w, off[W] = F.
__global__ void build_offsets_kernel(const int* __restrict__ seg,
                                     int* __restrict__ off, int F, int W) {
    int i = blockIdx.x * blockDim.x + threadIdx.x;
    if (i >= F) return;
    int s = seg[i];
    int p = (i == 0) ? -1 : seg[i - 1];
    for (int w = p + 1; w <= s; ++w) off[w] = i;
    if (i == F - 1) {
        for (int w = s + 1; w <= W; ++w) off[w] = F;
    }
}

// fp32 [NF][45] -> bf16(RNE) [NF][64] (128 B-aligned rows, pad garbage unread)
__global__ void convert_weights_kernel(const float* __restrict__ w,
                                       unsigned short* __restrict__ t,
                                       int total) {
    int i0 = (blockIdx.x * blockDim.x + threadIdx.x) * 4;
    if (i0 >= total) return;
    #pragma unroll
    for (int j = 0; j < 4; ++j) {
        int i = i0 + j;
        if (i < total) {
            unsigned u = __float_as_uint(w[i]);
            unsigned r = (u + 0x7FFFu + ((u >> 16) & 1u)) >> 16;   // RNE
            unsigned row = (unsigned)i / N_LABELS;
            unsigned col = (unsigned)i - row * N_LABELS;
            t[(size_t)row * ROWSTRIDE + col] = (unsigned short)r;
        }
    }
}

// One wave per WPW consecutive words, gathering from the packed bf16 table.
__global__ void tagger_bf16_kernel(const int* __restrict__ feat,
                                   const unsigned short* __restrict__ tb,
                                   const float* __restrict__ trigram_w,
                                   const int* __restrict__ off,
                                   float* __restrict__ out, int W, int F) {
    int gwave = (int)((blockIdx.x * blockDim.x + threadIdx.x) >> 6);
    gwave = __builtin_amdgcn_readfirstlane(gwave);
    int lane = (int)(threadIdx.x & 63);
    int w0 = gwave * WPW;
    if (w0 >= W) return;

    int ll = (lane < N_LABELS) ? lane : 0;

    int b[WPW + 1];
    #pragma unroll
    for (int k = 0; k <= WPW; ++k) {
        int w = w0 + k;
        b[k] = off[(w < W) ? w : W];
    }

    int beg = b[0];
    int my = feat[min(beg + lane, F - 1)];

    unsigned vals[WPW][GRP];
    int tri[WPW];
    int ncv[WPW];

    // ---- issue phase: fire all 1-line gathers ----
    #pragma unroll
    for (int k = 0; k < WPW; ++k) {
        int s = b[k], e = b[k + 1];
        int len = e - s;
        int rel = s - beg;
        int avail = 64 - min(rel, 64);
        int ncov = min(min(len, GRP), avail);
        ncv[k] = ncov;
        int lastj = (ncov > 0) ? (ncov - 1) : 0;
        tri[k] = 0;

        #pragma unroll
        for (int j = 0; j < 8; ++j) {
            int jc = (j < ncov) ? j : lastj;
            int p = min(rel + jc, 63);
            int idx = __builtin_amdgcn_readlane(my, p);     // SGPR
            tri[k] += (j < ncov) ? idx : 0;
            vals[k][j] = tb[(size_t)((unsigned)idx) * ROWSTRIDE + ll];
        }
        if (ncov > 8) {
            #pragma unroll
            for (int j = 8; j < GRP; ++j) {
                int jc = (j < ncov) ? j : lastj;
                int p = min(rel + jc, 63);
                int idx = __builtin_amdgcn_readlane(my, p);
                tri[k] += (j < ncov) ? idx : 0;
                vals[k][j] = tb[(size_t)((unsigned)idx) * ROWSTRIDE + ll];
            }
        }
    }

    asm volatile("" ::: "memory");

    float trig[WPW];
    #pragma unroll
    for (int k = 0; k < WPW; ++k) {
        int t = tri[k];
        if (t < 0) t = 0;
        if (t >= N_TRIGRAMS) t = N_TRIGRAMS - 1;
        trig[k] = trigram_w[t];
    }

    float acc[WPW];

    // ---- consume phase ----
    #pragma unroll
    for (int k = 0; k < WPW; ++k) {
        int s = b[k], e = b[k + 1];
        int ncov = ncv[k];
        float f[GRP];
        #pragma unroll
        for (int j = 0; j < GRP; ++j)
            f[j] = __uint_as_float(vals[k][j] << 16);
        float sum;
        if (ncov > 8) {
            int pad = GRP - ncov;
            float t0 = (f[0]  + f[1])  + (f[2]  + f[3]);
            float t1 = (f[4]  + f[5])  + (f[6]  + f[7]);
            float t2 = (f[8]  + f[9])  + (f[10] + f[11]);
            float t3 = (f[12] + f[13]) + (f[14] + f[15]);
            sum = ((t0 + t1) + (t2 + t3)) - (float)pad * f[GRP - 1];
        } else {
            int pad = 8 - ncov;
            float t0 = (f[0] + f[1]) + (f[2] + f[3]);
            float t1 = (f[4] + f[5]) + (f[6] + f[7]);
            sum = (t0 + t1) - (float)pad * f[7];
        }
        acc[k] = sum;

        if (s + ncov < e) {   // rare slow remainder
            for (int base2 = s + ncov; base2 < e; base2 += 64) {
                int cnt = min(64, e - base2);
                int m2 = feat[base2 + ((lane < cnt) ? lane : 0)];
                for (int g = 0; g < cnt; g += 8) {
                    float v2[8];
                    int lastE = cnt - 1;
                    #pragma unroll
                    for (int j = 0; j < 8; ++j) {
                        int e2 = g + j;
                        int ec = (e2 < cnt) ? e2 : lastE;
                        int idx = __builtin_amdgcn_readlane(m2, ec);
                        tri[k] += (e2 < cnt) ? idx : 0;
                        unsigned us = tb[(size_t)((unsigned)idx) * ROWSTRIDE + ll];
                        v2[j] = __uint_as_float(us << 16);
                    }
                    int pad2 = (g + 8 > cnt) ? (g + 8 - cnt) : 0;
                    float s01 = v2[0] + v2[1], s23 = v2[2] + v2[3];
                    float s45 = v2[4] + v2[5], s67 = v2[6] + v2[7];
                    acc[k] += ((s01 + s23) + (s45 + s67)) - (float)pad2 * v2[7];
                }
            }
            int t = tri[k];
            if (t < 0) t = 0;
            if (t >= N_TRIGRAMS) t = N_TRIGRAMS - 1;
            trig[k] = trigram_w[t];
        }
    }

    #pragma unroll
    for (int k = 0; k < WPW; ++k) {
        int w = w0 + k;
        if (lane < N_LABELS && w < W)
            out[(long long)w * N_LABELS + lane] = acc[k] + trig[k];
    }
}

// Fallback (round-5 fp32 path) if ws is too small for the packed table.
__global__ void tagger_f32_kernel(const int* __restrict__ feat,
                                  const float* __restrict__ weights,
                                  const float* __restrict__ trigram_w,
                                  const int* __restrict__ off,
                                  float* __restrict__ out, int W, int F) {
    int gwave = (int)((blockIdx.x * blockDim.x + threadIdx.x) >> 6);
    gwave = __builtin_amdgcn_readfirstlane(gwave);
    int lane = (int)(threadIdx.x & 63);
    int w0 = gwave * WPW;
    if (w0 >= W) return;
    int ll = (lane < N_LABELS) ? lane : 0;
    int b[WPW + 1];
    #pragma unroll
    for (int k = 0; k <= WPW; ++k) {
        int w = w0 + k;
        b[k] = off[(w < W) ? w : W];
    }
    int beg = b[0];
    int my = feat[min(beg + lane, F - 1)];
    float vals[WPW][GRP];
    int tri[WPW], ncv[WPW];
    #pragma unroll
    for (int k = 0; k < WPW; ++k) {
        int s = b[k], e = b[k + 1];
        int len = e - s, rel = s - beg;
        int avail = 64 - min(rel, 64);
        int ncov = min(min(len, GRP), avail);
        ncv[k] = ncov;
        int lastj = (ncov > 0) ? (ncov - 1) : 0;
        tri[k] = 0;
        #pragma unroll
        for (int j = 0; j < GRP; ++j) {
            int jc = (j < ncov) ? j : lastj;
            int p = min(rel + jc, 63);
            int idx = __builtin_amdgcn_readlane(my, p);
            tri[k] += (j < ncov) ? idx : 0;
            vals[k][j] = weights[(unsigned)idx * N_LABELS + ll];
        }
    }
    asm volatile("" ::: "memory");
    float trig[WPW];
    #pragma unroll
    for (int k = 0; k < WPW; ++k) {
        int t = tri[k];
        t = (t < 0) ? 0 : ((t >= N_TRIGRAMS) ? N_TRIGRAMS - 1 : t);
        trig[k] = trigram_w[t];
    }
    float acc[WPW];
    #pragma unroll
    for (int k = 0; k < WPW; ++k) {
        int s = b[k], e = b[k + 1];
        int ncov = ncv[k];
        int pad = GRP - ncov;
        float t0 = (vals[k][0]  + vals[k][1])  + (vals[k][2]  + vals[k][3]);
        float t1 = (vals[k][4]  + vals[k][5])  + (vals[k][6]  + vals[k][7]);
        float t2 = (vals[k][8]  + vals[k][9])  + (vals[k][10] + vals[k][11]);
        float t3 = (vals[k][12] + vals[k][13]) + (vals[k][14] + vals[k][15]);
        acc[k] = ((t0 + t1) + (t2 + t3)) - (float)pad * vals[k][GRP - 1];
        if (s + ncov < e) {
            for (int base2 = s + ncov; base2 < e; base2 += 64) {
                int cnt = min(64, e - base2);
                int m2 = feat[base2 + ((lane < cnt) ? lane : 0)];
                for (int g = 0; g < cnt; g += 8) {
                    float v2[8];
                    int lastE = cnt - 1;
                    #pragma unroll
                    for (int j = 0; j < 8; ++j) {
                        int e2 = g + j;
                        int ec = (e2 < cnt) ? e2 : lastE;
                        int idx = __builtin_amdgcn_readlane(m2, ec);
                        tri[k] += (e2 < cnt) ? idx : 0;
                        v2[j] = weights[(unsigned)idx * N_LABELS + ll];
                    }
                    int pad2 = (g + 8 > cnt) ? (g + 8 - cnt) : 0;
                    acc[k] += ((v2[0]+v2[1])+(v2[2]+v2[3])+(v2[4]+v2[5])+(v2[6]+v2[7]))
                              - (float)pad2 * v2[7];
                }
            }
            int t = tri[k];
            t = (t < 0) ? 0 : ((t >= N_TRIGRAMS) ? N_TRIGRAMS - 1 : t);
            trig[k] = trigram_w[t];
        }
    }
    #pragma unroll
    for (int k = 0; k < WPW; ++k) {
        int w = w0 + k;
        if (lane < N_LABELS && w < W)
            out[(long long)w * N_LABELS + lane] = acc[k] + trig[k];
    }
}

extern "C" void kernel_launch(void* const* d_in, const int* in_sizes, int n_in,
                              void* d_out, int out_size, void* d_ws, size_t ws_size,
                              hipStream_t stream) {
    const int*   feat      = (const int*)d_in[0];
    const int*   seg       = (const int*)d_in[1];
    const float* weights   = (const float*)d_in[2];
    const float* trigram_w = (const float*)d_in[3];
    float*       out       = (float*)d_out;

    int F  = in_sizes[0];
    int W  = out_size / N_LABELS;
    int NF = in_sizes[2] / N_LABELS;

    int* off = (int*)d_ws;
    size_t table_off = ((size_t)(W + 1) * 4 + 255) & ~(size_t)255;
    size_t need = table_off + (size_t)NF * ROWSTRIDE * 2;

    {
        int threads = 256;
        int blocks = (F + threads - 1) / threads;
        build_offsets_kernel<<<blocks, threads, 0, stream>>>(seg, off, F, W);
    }

    int threads = 256;
    int wavesPerBlock = threads / 64;
    int nWaves = (W + WPW - 1) / WPW;
    int blocks = (nWaves + wavesPerBlock - 1) / wavesPerBlock;

    if (ws_size >= need) {
        unsigned short* tb = (unsigned short*)((char*)d_ws + table_off);
        int total = NF * N_LABELS;
        int cthreads = 256;
        int cblocks = (total / 4 + cthreads - 1) / cthreads + 1;
        convert_weights_kernel<<<cblocks, cthreads, 0, stream>>>(weights, tb, total);
        tagger_bf16_kernel<<<blocks, threads, 0, stream>>>(feat, tb, trigram_w,
                                                           off, out, W, F);
    } else {
        tagger_f32_kernel<<<blocks, threads, 0, stream>>>(feat, weights, trigram_w,
                                                          off, out, W, F);
    }
}